// Round 1
// baseline (206.782 us; speedup 1.0000x reference)
//
#include <hip/hip_runtime.h>

// CP-decomposed 3D conv (AirConv3D): B=1, Cin=32, Cout=64, 56^3, K=3, pad=1, rank=53.
// All-f32. ws ~268 MB. R9 lesson: block-splitting a reduction reader
// multiplies HBM traffic (no cross-XCD L2 reuse) — single-pass readers only.
// R11 (this round): DELETE k2w. w-conv fused into k3 as a read-side 9-point
// stencil (3h x 3w float2 loads per rank; w+-1 = +-28 float2 -> L1/L2 hits).
// Pipeline: k0_t -> k1d (pointwise+d-conv via shfl) -> k3wh (w+h conv + 53->64
// proj + bias). T1 round-trips drop from 4 to 2 (148.8 -> 74.4 MB on T1).
// Fallback (small ws): R5 pipeline (known good).

#define NP 175616   // 56*56*56
#define NP2 87808   // NP/2 float2 columns
#define HSTR 3136   // 56*56
#define H2 1568     // HSTR/2 float2 per h-plane
#define W2 28       // 56/2 float2 per w-row
#define QH 784      // HSTR/4 quads per h-plane
#define CIN 32
#define RK 53
#define COUT 64
#define SCR 53      // fallback scratch slice base in d_out

// ---- k0: Ut[r*32+c] = Ucin[c*53+r] ----
__global__ __launch_bounds__(256) void k0_t(const float* __restrict__ Ucin,
                                            float* __restrict__ Ut)
{
    int t = blockIdx.x * 256 + threadIdx.x;
    if (t < RK * CIN) {
        int r = t >> 5, c = t & 31;
        Ut[t] = Ucin[c * RK + r];
    }
}

// ---- k1d: T1d[r,p] = d-conv(sum_c x[c,p]*Ut[r][c]) via wave shfl ----
// Block = 256 threads = 4 waves; wave = one d-row (lanes 0..55 active).
__global__ __launch_bounds__(256) void k1d(
    const float* __restrict__ x, const float* __restrict__ Ut,
    const float* __restrict__ Ukd, float* __restrict__ T1d)
{
    const int lane = threadIdx.x & 63;          // d index
    const int row  = blockIdx.x * 4 + (threadIdx.x >> 6);   // (h,w) row in [0,3136)
    const int p    = row * 56 + lane;
    const bool act = (lane < 56);

    float xv[CIN];
#pragma unroll
    for (int c = 0; c < CIN; ++c) xv[c] = act ? x[c * NP + p] : 0.f;

#pragma unroll 2
    for (int r = 0; r < RK; ++r) {
        const float* U = Ut + r * CIN;          // uniform -> s_load
        float acc = 0.f;
#pragma unroll
        for (int c = 0; c < CIN; ++c) acc += xv[c] * U[c];
        // d-conv: out[d] = in[d-1]*kd0 + in[d]*kd1 + in[d+1]*kd2, zero pad
        float lm = __shfl_up(acc, 1, 64);
        float rp = __shfl_down(acc, 1, 64);
        if (lane == 0)  lm = 0.f;
        if (lane == 55) rp = 0.f;
        float res = lm * Ukd[r] + acc * Ukd[RK + r] + rp * Ukd[2 * RK + r];
        if (act) T1d[(size_t)r * NP + p] = res;
    }
}

// ---- k3wh: w-conv + h-conv + 53->64 projection + bias, single pass ----
// out[o,q] = sum_r hblend(wblend(Ta[r, h-1..h+1, w-1..w+1, q])) * Ucout[r][o] + b
// float2 lanes: 1372 blocks x 4 waves; wave owns 16 out-channels (og uniform).
__global__ __launch_bounds__(256, 4) void k3wh(
    const float2* __restrict__ Ta, const float* __restrict__ Ucout,
    const float* __restrict__ bias, const float* __restrict__ Ukh,
    const float* __restrict__ Ukw, float2* __restrict__ Out)
{
    const int lane = threadIdx.x & 63;
    int og = (threadIdx.x >> 6) << 4;            // 0,16,32,48
    og = __builtin_amdgcn_readfirstlane(og);
    const int q  = blockIdx.x * 64 + lane;       // float2 column in [0,NP2)
    const int h  = q / H2;
    const int q2 = q - h * H2;                   // float2 idx within h-plane
    const int w  = q2 / W2;
    const bool hm = (h > 0), hp = (h < 55);
    const bool wm = (w > 0), wp = (w < 55);

    float2 a[16];
#pragma unroll
    for (int o = 0; o < 16; ++o) {
        float b = bias[og + o];
        a[o].x = b; a[o].y = b;
    }
#pragma unroll 2
    for (int r = 0; r < RK; ++r) {
        const float2* S = Ta + (size_t)r * NP2 + q;
        const float kh0 = Ukh[r], kh1 = Ukh[RK + r], kh2 = Ukh[2 * RK + r];
        const float kw0 = Ukw[r], kw1 = Ukw[RK + r], kw2 = Ukw[2 * RK + r];

        float2 row0, row1, row2;
        row0.x = row0.y = 0.f;
        row2 = row0;
        // center h row (always valid)
        {
            float2 B = S[0];
            float2 A, C;
            A.x = A.y = 0.f; C = A;
            if (wm) A = S[-W2];
            if (wp) C = S[W2];
            row1.x = A.x * kw0 + B.x * kw1 + C.x * kw2;
            row1.y = A.y * kw0 + B.y * kw1 + C.y * kw2;
        }
        if (hm) {
            const float2* Sh = S - H2;
            float2 B = Sh[0];
            float2 A, C;
            A.x = A.y = 0.f; C = A;
            if (wm) A = Sh[-W2];
            if (wp) C = Sh[W2];
            row0.x = A.x * kw0 + B.x * kw1 + C.x * kw2;
            row0.y = A.y * kw0 + B.y * kw1 + C.y * kw2;
        }
        if (hp) {
            const float2* Sh = S + H2;
            float2 B = Sh[0];
            float2 A, C;
            A.x = A.y = 0.f; C = A;
            if (wm) A = Sh[-W2];
            if (wp) C = Sh[W2];
            row2.x = A.x * kw0 + B.x * kw1 + C.x * kw2;
            row2.y = A.y * kw0 + B.y * kw1 + C.y * kw2;
        }

        float2 t;
        t.x = row0.x * kh0 + row1.x * kh1 + row2.x * kh2;
        t.y = row0.y * kh0 + row1.y * kh1 + row2.y * kh2;

        const float* Ur = Ucout + r * COUT + og;   // uniform -> s_load
#pragma unroll
        for (int o = 0; o < 16; ++o) {
            float u = Ur[o];
            a[o].x += t.x * u; a[o].y += t.y * u;
        }
    }
#pragma unroll
    for (int o = 0; o < 16; ++o)
        Out[(size_t)(og + o) * NP2 + q] = a[o];
}

// ===================== fallback path (R5, known good) =====================

__global__ __launch_bounds__(256) void k1_chunk(
    const float* __restrict__ x, const float* __restrict__ Ucin,
    float* T, int r0, int nr)
{
    __shared__ float sU[11 * CIN];
    const int tid = threadIdx.x;
    for (int t = tid; t < nr * CIN; t += 256) {
        int lr = t >> 5, c = t & 31;
        sU[t] = Ucin[c * RK + (r0 + lr)];
    }
    __syncthreads();
    const int p = blockIdx.x * 256 + tid;
    float xv[CIN];
#pragma unroll
    for (int c = 0; c < CIN; ++c) xv[c] = x[c * NP + p];
#pragma unroll 1
    for (int lr = 0; lr < nr; ++lr) {
        float acc = 0.f;
#pragma unroll
        for (int c = 0; c < CIN; ++c) acc += xv[c] * sU[lr * CIN + c];
        T[(size_t)(SCR + lr) * NP + p] = acc;
    }
}

__global__ __launch_bounds__(256) void k2_chunk(
    const float* __restrict__ Ukh, const float* __restrict__ Ukw,
    const float* __restrict__ Ukd, float* T, int r0)
{
    __shared__ float sIn[5800];
    __shared__ float sA[5600];
    const int lr = blockIdx.z;
    const int r  = r0 + lr;
    const int h0 = blockIdx.x * 8, w0 = blockIdx.y * 8;
    const int tid = threadIdx.x;
    const float kh0 = Ukh[r], kh1 = Ukh[RK + r], kh2 = Ukh[2 * RK + r];
    const float kw0 = Ukw[r], kw1 = Ukw[RK + r], kw2 = Ukw[2 * RK + r];
    const float kd0 = Ukd[r], kd1 = Ukd[RK + r], kd2 = Ukd[2 * RK + r];
    const float* T1r = T + (size_t)(SCR + lr) * NP;

    for (int idx = tid; idx < 5800; idx += 256) {
        int d = idx % 58; int t2 = idx / 58; int ww = t2 % 10; int hh = t2 / 10;
        int gh = h0 + hh - 1, gw = w0 + ww - 1, gd = d - 1;
        float v = 0.f;
        if ((unsigned)gh < 56u && (unsigned)gw < 56u && (unsigned)gd < 56u)
            v = T1r[gh * HSTR + gw * 56 + gd];
        sIn[idx] = v;
    }
    __syncthreads();
    for (int idx = tid; idx < 5600; idx += 256) {
        int d = idx % 56; int t2 = idx / 56; int ww = t2 % 10; int hh = t2 / 10;
        const float* b = &sIn[(hh * 10 + ww) * 58 + d];
        sA[idx] = b[0] * kd0 + b[1] * kd1 + b[2] * kd2;
    }
    __syncthreads();
    const float k00 = kh0 * kw0, k01 = kh0 * kw1, k02 = kh0 * kw2;
    const float k10 = kh1 * kw0, k11 = kh1 * kw1, k12 = kh1 * kw2;
    const float k20 = kh2 * kw0, k21 = kh2 * kw1, k22 = kh2 * kw2;
    for (int idx = tid; idx < 3584; idx += 256) {
        int d = idx % 56; int t2 = idx / 56; int ww = t2 % 8; int hh = t2 / 8;
        const float* a = &sA[(hh * 10 + ww) * 56 + d];
        float acc = a[0]    * k00 + a[56]   * k01 + a[112]  * k02
                  + a[560]  * k10 + a[616]  * k11 + a[672]  * k12
                  + a[1120] * k20 + a[1176] * k21 + a[1232] * k22;
        T[(size_t)r * NP + (h0 + hh) * HSTR + (w0 + ww) * 56 + d] = acc;
    }
}

__global__ __launch_bounds__(256) void k3_out(
    float* T, const float* __restrict__ Ucout, const float* __restrict__ bias)
{
    __shared__ float sUo[RK * COUT];
    __shared__ float sB[COUT];
    const int tid = threadIdx.x;
    for (int t = tid; t < RK * COUT; t += 256) sUo[t] = Ucout[t];
    if (tid < COUT) sB[tid] = bias[tid];
    __syncthreads();
    const int p = blockIdx.x * 256 + tid;
    float acc[COUT];
#pragma unroll
    for (int o = 0; o < COUT; ++o) acc[o] = sB[o];
#pragma unroll 1
    for (int r = 0; r < RK; ++r) {
        float t = T[(size_t)r * NP + p];
        const float* Ur = &sUo[r * COUT];
#pragma unroll
        for (int o = 0; o < COUT; ++o) acc[o] += t * Ur[o];
    }
#pragma unroll
    for (int o = 0; o < COUT; ++o) T[(size_t)o * NP + p] = acc[o];
}

// ===================== launch =====================

extern "C" void kernel_launch(void* const* d_in, const int* in_sizes, int n_in,
                              void* d_out, int out_size, void* d_ws, size_t ws_size,
                              hipStream_t stream)
{
    const float* x     = (const float*)d_in[0];
    const float* Ukh   = (const float*)d_in[1];
    const float* Ukw   = (const float*)d_in[2];
    const float* Ukd   = (const float*)d_in[3];
    const float* Ucin  = (const float*)d_in[4];
    const float* Ucout = (const float*)d_in[5];
    const float* bias  = (const float*)d_in[6];

    const size_t t1_bytes = (size_t)RK * NP * sizeof(float);   // 37.2 MB

    if (ws_size >= t1_bytes + 8192) {
        float* T1 = (float*)d_ws;
        float* Ut = (float*)((char*)d_ws + t1_bytes);          // 6.8 KB
        k0_t<<<7, 256, 0, stream>>>(Ucin, Ut);
        k1d<<<HSTR / 4, 256, 0, stream>>>(x, Ut, Ukd, T1);     // 784 blocks
        k3wh<<<NP2 / 64, 256, 0, stream>>>((const float2*)T1, Ucout, bias, Ukh,
                                           Ukw, (float2*)d_out);
    } else {
        float* T = (float*)d_out;
        for (int r0 = 0; r0 < RK; r0 += 11) {
            int nr = (RK - r0 < 11) ? (RK - r0) : 11;
            k1_chunk<<<NP / 256, 256, 0, stream>>>(x, Ucin, T, r0, nr);
            k2_chunk<<<dim3(7, 7, nr), 256, 0, stream>>>(Ukh, Ukw, Ukd, T, r0);
        }
        k3_out<<<NP / 256, 256, 0, stream>>>(T, Ucout, bias);
    }
}

// Round 3
// 180.228 us; speedup vs baseline: 1.1473x; 1.1473x over previous
//
#include <hip/hip_runtime.h>

// CP-decomposed 3D conv (AirConv3D): B=1, Cin=32, Cout=64, 56^3, K=3, pad=1, rank=53.
// All-f32. ws ~268 MB. R9 lesson: block-splitting a reduction reader
// multiplies HBM traffic (no cross-XCD L2 reuse) — single-pass readers only.
// R11 lesson: fused 9-pt gather with per-load exec-mask branches + 4x redundant
// wave loads = latency-bound (102 us @ 12% BW, VGPR=36, no pipelining).
// R12 (resubmitted after infra failure): k3wh rebuilt:
//   - branchless: boundary -> offset-select (once/thread) + weight-zero (cndmask),
//     all 9 loads unconditional
//   - rank-split: wave wv computes stencil t[r] for r = wv mod 4 -> LDS (26.5 KB),
//     barrier, then each wave projects its 16 channels reading t from LDS.
//     Global load issue /4, 13-14 independent iters/wave for MLP.
// Pipeline: k0_t -> k1d (pointwise+d-conv via shfl) -> k3wh (w+h conv + proj + bias).
// Fallback (small ws): R5 pipeline (known good).

#define NP 175616   // 56*56*56
#define NP2 87808   // NP/2 float2 columns
#define HSTR 3136   // 56*56
#define H2 1568     // HSTR/2 float2 per h-plane
#define W2 28       // 56/2 float2 per w-row
#define QH 784      // HSTR/4 quads per h-plane
#define CIN 32
#define RK 53
#define COUT 64
#define SCR 53      // fallback scratch slice base in d_out

// ---- k0: Ut[r*32+c] = Ucin[c*53+r] ----
__global__ __launch_bounds__(256) void k0_t(const float* __restrict__ Ucin,
                                            float* __restrict__ Ut)
{
    int t = blockIdx.x * 256 + threadIdx.x;
    if (t < RK * CIN) {
        int r = t >> 5, c = t & 31;
        Ut[t] = Ucin[c * RK + r];
    }
}

// ---- k1d: T1d[r,p] = d-conv(sum_c x[c,p]*Ut[r][c]) via wave shfl ----
// Block = 256 threads = 4 waves; wave = one d-row (lanes 0..55 active).
__global__ __launch_bounds__(256) void k1d(
    const float* __restrict__ x, const float* __restrict__ Ut,
    const float* __restrict__ Ukd, float* __restrict__ T1d)
{
    const int lane = threadIdx.x & 63;          // d index
    const int row  = blockIdx.x * 4 + (threadIdx.x >> 6);   // (h,w) row in [0,3136)
    const int p    = row * 56 + lane;
    const bool act = (lane < 56);

    float xv[CIN];
#pragma unroll
    for (int c = 0; c < CIN; ++c) xv[c] = act ? x[c * NP + p] : 0.f;

#pragma unroll 2
    for (int r = 0; r < RK; ++r) {
        const float* U = Ut + r * CIN;          // uniform -> s_load
        float acc = 0.f;
#pragma unroll
        for (int c = 0; c < CIN; ++c) acc += xv[c] * U[c];
        // d-conv: out[d] = in[d-1]*kd0 + in[d]*kd1 + in[d+1]*kd2, zero pad
        float lm = __shfl_up(acc, 1, 64);
        float rp = __shfl_down(acc, 1, 64);
        if (lane == 0)  lm = 0.f;
        if (lane == 55) rp = 0.f;
        float res = lm * Ukd[r] + acc * Ukd[RK + r] + rp * Ukd[2 * RK + r];
        if (act) T1d[(size_t)r * NP + p] = res;
    }
}

// ---- k3wh: w-conv + h-conv + 53->64 projection + bias, single pass ----
// Phase 1: wave wv computes t[r] = hblend(wblend(Ta[r,...])) for r=wv,wv+4,...
//          -> LDS. Branchless (offset-select + weight-zero). 9 loads/rank, once.
// Phase 2: each wave projects 16 out-channels from LDS t[0..52].
__global__ __launch_bounds__(256, 4) void k3wh(
    const float2* __restrict__ Ta, const float* __restrict__ Ucout,
    const float* __restrict__ bias, const float* __restrict__ Ukh,
    const float* __restrict__ Ukw, float2* __restrict__ Out)
{
    __shared__ float2 tld[RK][64];               // 53*64*8 = 26.5 KB

    const int lane = threadIdx.x & 63;
    const int wv   = threadIdx.x >> 6;
    const int q    = blockIdx.x * 64 + lane;     // float2 column in [0,NP2)
    const int h    = q / H2;
    const int q2   = q - h * H2;                 // float2 idx within h-plane
    const int w    = q2 / W2;
    const bool hm = (h > 0), hp = (h < 55);
    const bool wm = (w > 0), wp = (w < 55);
    // boundary -> address select (computed once; all loads below are in-bounds)
    const int om = hm ? -H2 : 0;
    const int op = hp ?  H2 : 0;
    const int oa = wm ? -W2 : 0;
    const int oc = wp ?  W2 : 0;

    const float2* Sq = Ta + q;

    // ---- phase 1: stencil for ranks wv, wv+4, ... ----
#pragma unroll 2
    for (int r = wv; r < RK; r += 4) {
        const float2* S = Sq + (size_t)r * NP2;
        // boundary -> weight zero (cndmask, no branches)
        const float kw0 = wm ? Ukw[r] : 0.f;
        const float kw1 = Ukw[RK + r];
        const float kw2 = wp ? Ukw[2 * RK + r] : 0.f;
        const float kh0 = hm ? Ukh[r] : 0.f;
        const float kh1 = Ukh[RK + r];
        const float kh2 = hp ? Ukh[2 * RK + r] : 0.f;

        // 9 unconditional loads
        float2 v00 = S[om + oa], v01 = S[om], v02 = S[om + oc];
        float2 v10 = S[oa],      v11 = S[0],  v12 = S[oc];
        float2 v20 = S[op + oa], v21 = S[op], v22 = S[op + oc];

        float2 r0, r1, r2, t;
        r0.x = v00.x * kw0 + v01.x * kw1 + v02.x * kw2;
        r0.y = v00.y * kw0 + v01.y * kw1 + v02.y * kw2;
        r1.x = v10.x * kw0 + v11.x * kw1 + v12.x * kw2;
        r1.y = v10.y * kw0 + v11.y * kw1 + v12.y * kw2;
        r2.x = v20.x * kw0 + v21.x * kw1 + v22.x * kw2;
        r2.y = v20.y * kw0 + v21.y * kw1 + v22.y * kw2;
        t.x  = r0.x * kh0 + r1.x * kh1 + r2.x * kh2;
        t.y  = r0.y * kh0 + r1.y * kh1 + r2.y * kh2;
        tld[r][lane] = t;
    }
    __syncthreads();

    // ---- phase 2: 16-channel projection per wave ----
    const int og = wv << 4;                      // 0,16,32,48 (wave-uniform)
    float2 a[16];
#pragma unroll
    for (int o = 0; o < 16; ++o) {
        float b = bias[og + o];
        a[o].x = b; a[o].y = b;
    }
#pragma unroll 2
    for (int r = 0; r < RK; ++r) {
        float2 t = tld[r][lane];
        const float* Ur = Ucout + r * COUT + og; // uniform -> s_load
#pragma unroll
        for (int o = 0; o < 16; ++o) {
            float u = Ur[o];
            a[o].x += t.x * u; a[o].y += t.y * u;
        }
    }
#pragma unroll
    for (int o = 0; o < 16; ++o)
        Out[(size_t)(og + o) * NP2 + q] = a[o];
}

// ===================== fallback path (R5, known good) =====================

__global__ __launch_bounds__(256) void k1_chunk(
    const float* __restrict__ x, const float* __restrict__ Ucin,
    float* T, int r0, int nr)
{
    __shared__ float sU[11 * CIN];
    const int tid = threadIdx.x;
    for (int t = tid; t < nr * CIN; t += 256) {
        int lr = t >> 5, c = t & 31;
        sU[t] = Ucin[c * RK + (r0 + lr)];
    }
    __syncthreads();
    const int p = blockIdx.x * 256 + tid;
    float xv[CIN];
#pragma unroll
    for (int c = 0; c < CIN; ++c) xv[c] = x[c * NP + p];
#pragma unroll 1
    for (int lr = 0; lr < nr; ++lr) {
        float acc = 0.f;
#pragma unroll
        for (int c = 0; c < CIN; ++c) acc += xv[c] * sU[lr * CIN + c];
        T[(size_t)(SCR + lr) * NP + p] = acc;
    }
}

__global__ __launch_bounds__(256) void k2_chunk(
    const float* __restrict__ Ukh, const float* __restrict__ Ukw,
    const float* __restrict__ Ukd, float* T, int r0)
{
    __shared__ float sIn[5800];
    __shared__ float sA[5600];
    const int lr = blockIdx.z;
    const int r  = r0 + lr;
    const int h0 = blockIdx.x * 8, w0 = blockIdx.y * 8;
    const int tid = threadIdx.x;
    const float kh0 = Ukh[r], kh1 = Ukh[RK + r], kh2 = Ukh[2 * RK + r];
    const float kw0 = Ukw[r], kw1 = Ukw[RK + r], kw2 = Ukw[2 * RK + r];
    const float kd0 = Ukd[r], kd1 = Ukd[RK + r], kd2 = Ukd[2 * RK + r];
    const float* T1r = T + (size_t)(SCR + lr) * NP;

    for (int idx = tid; idx < 5800; idx += 256) {
        int d = idx % 58; int t2 = idx / 58; int ww = t2 % 10; int hh = t2 / 10;
        int gh = h0 + hh - 1, gw = w0 + ww - 1, gd = d - 1;
        float v = 0.f;
        if ((unsigned)gh < 56u && (unsigned)gw < 56u && (unsigned)gd < 56u)
            v = T1r[gh * HSTR + gw * 56 + gd];
        sIn[idx] = v;
    }
    __syncthreads();
    for (int idx = tid; idx < 5600; idx += 256) {
        int d = idx % 56; int t2 = idx / 56; int ww = t2 % 10; int hh = t2 / 10;
        const float* b = &sIn[(hh * 10 + ww) * 58 + d];
        sA[idx] = b[0] * kd0 + b[1] * kd1 + b[2] * kd2;
    }
    __syncthreads();
    const float k00 = kh0 * kw0, k01 = kh0 * kw1, k02 = kh0 * kw2;
    const float k10 = kh1 * kw0, k11 = kh1 * kw1, k12 = kh1 * kw2;
    const float k20 = kh2 * kw0, k21 = kh2 * kw1, k22 = kh2 * kw2;
    for (int idx = tid; idx < 3584; idx += 256) {
        int d = idx % 56; int t2 = idx / 56; int ww = t2 % 8; int hh = t2 / 8;
        const float* a = &sA[(hh * 10 + ww) * 56 + d];
        float acc = a[0]    * k00 + a[56]   * k01 + a[112]  * k02
                  + a[560]  * k10 + a[616]  * k11 + a[672]  * k12
                  + a[1120] * k20 + a[1176] * k21 + a[1232] * k22;
        T[(size_t)r * NP + (h0 + hh) * HSTR + (w0 + ww) * 56 + d] = acc;
    }
}

__global__ __launch_bounds__(256) void k3_out(
    float* T, const float* __restrict__ Ucout, const float* __restrict__ bias)
{
    __shared__ float sUo[RK * COUT];
    __shared__ float sB[COUT];
    const int tid = threadIdx.x;
    for (int t = tid; t < RK * COUT; t += 256) sUo[t] = Ucout[t];
    if (tid < COUT) sB[tid] = bias[tid];
    __syncthreads();
    const int p = blockIdx.x * 256 + tid;
    float acc[COUT];
#pragma unroll
    for (int o = 0; o < COUT; ++o) acc[o] = sB[o];
#pragma unroll 1
    for (int r = 0; r < RK; ++r) {
        float t = T[(size_t)r * NP + p];
        const float* Ur = &sUo[r * COUT];
#pragma unroll
        for (int o = 0; o < COUT; ++o) acc[o] += t * Ur[o];
    }
#pragma unroll
    for (int o = 0; o < COUT; ++o) T[(size_t)o * NP + p] = acc[o];
}

// ===================== launch =====================

extern "C" void kernel_launch(void* const* d_in, const int* in_sizes, int n_in,
                              void* d_out, int out_size, void* d_ws, size_t ws_size,
                              hipStream_t stream)
{
    const float* x     = (const float*)d_in[0];
    const float* Ukh   = (const float*)d_in[1];
    const float* Ukw   = (const float*)d_in[2];
    const float* Ukd   = (const float*)d_in[3];
    const float* Ucin  = (const float*)d_in[4];
    const float* Ucout = (const float*)d_in[5];
    const float* bias  = (const float*)d_in[6];

    const size_t t1_bytes = (size_t)RK * NP * sizeof(float);   // 37.2 MB

    if (ws_size >= t1_bytes + 8192) {
        float* T1 = (float*)d_ws;
        float* Ut = (float*)((char*)d_ws + t1_bytes);          // 6.8 KB
        k0_t<<<7, 256, 0, stream>>>(Ucin, Ut);
        k1d<<<HSTR / 4, 256, 0, stream>>>(x, Ut, Ukd, T1);     // 784 blocks
        k3wh<<<NP2 / 64, 256, 0, stream>>>((const float2*)T1, Ucout, bias, Ukh,
                                           Ukw, (float2*)d_out);
    } else {
        float* T = (float*)d_out;
        for (int r0 = 0; r0 < RK; r0 += 11) {
            int nr = (RK - r0 < 11) ? (RK - r0) : 11;
            k1_chunk<<<NP / 256, 256, 0, stream>>>(x, Ucin, T, r0, nr);
            k2_chunk<<<dim3(7, 7, nr), 256, 0, stream>>>(Ukh, Ukw, Ukd, T, r0);
        }
        k3_out<<<NP / 256, 256, 0, stream>>>(T, Ucout, bias);
    }
}

// Round 4
// 159.348 us; speedup vs baseline: 1.2977x; 1.1310x over previous
//
#include <hip/hip_runtime.h>

// CP-decomposed 3D conv (AirConv3D): B=1, Cin=32, Cout=64, 56^3, K=3, pad=1, rank=53.
// All-f32. ws ~268 MB. R9 lesson: block-splitting a reduction reader
// multiplies HBM traffic (no cross-XCD L2 reuse) — single-pass readers only.
// R11 lesson: per-load exec-mask branches + redundant wave loads = latency-bound.
// R12 lesson: branchless + rank-split got 102->74 us but float2 loads + 4-wave
// blocks leave bytes-in-flight ~1.8 KB/CU -> 1.37 TB/s latency-bound.
// NOTE: measured dur_us carries ~90 us of harness fillBuffer (ws re-poison);
// our pipeline is k3 (dominant) + k1d ~14 us (near its traffic roofline) + k0.
// R13: k3wh4 = float4 lanes (d has no stencil -> free 16B vectors), 8-wave
// blocks, rank-split 8, LDS tld[53][64]xfloat4 (54.3 KB, 2 blocks/CU,
// 16 waves/CU), 8 channels/wave in phase 2, bijective XCD swizzle (halo L2
// locality). Target: k3 74 -> ~25-30 us (BW-bound at ~4 TB/s).
// Pipeline: k0_t -> k1d (pointwise+d-conv via shfl) -> k3wh4.
// Fallback (small ws): R5 pipeline (known good).

#define NP 175616   // 56*56*56
#define NP2 87808   // NP/2 float2 columns
#define NP4 43904   // NP/4 float4 columns
#define HSTR 3136   // 56*56
#define H2 1568     // HSTR/2 float2 per h-plane
#define H4 784      // HSTR/4 float4 per h-plane
#define W2 28       // 56/2 float2 per w-row
#define W4 14       // 56/4 float4 per w-row
#define QH 784      // HSTR/4 quads per h-plane
#define CIN 32
#define RK 53
#define COUT 64
#define SCR 53      // fallback scratch slice base in d_out

// ---- k0: Ut[r*32+c] = Ucin[c*53+r] ----
__global__ __launch_bounds__(256) void k0_t(const float* __restrict__ Ucin,
                                            float* __restrict__ Ut)
{
    int t = blockIdx.x * 256 + threadIdx.x;
    if (t < RK * CIN) {
        int r = t >> 5, c = t & 31;
        Ut[t] = Ucin[c * RK + r];
    }
}

// ---- k1d: T1d[r,p] = d-conv(sum_c x[c,p]*Ut[r][c]) via wave shfl ----
// Block = 256 threads = 4 waves; wave = one d-row (lanes 0..55 active).
__global__ __launch_bounds__(256) void k1d(
    const float* __restrict__ x, const float* __restrict__ Ut,
    const float* __restrict__ Ukd, float* __restrict__ T1d)
{
    const int lane = threadIdx.x & 63;          // d index
    const int row  = blockIdx.x * 4 + (threadIdx.x >> 6);   // (h,w) row in [0,3136)
    const int p    = row * 56 + lane;
    const bool act = (lane < 56);

    float xv[CIN];
#pragma unroll
    for (int c = 0; c < CIN; ++c) xv[c] = act ? x[c * NP + p] : 0.f;

#pragma unroll 2
    for (int r = 0; r < RK; ++r) {
        const float* U = Ut + r * CIN;          // uniform -> s_load
        float acc = 0.f;
#pragma unroll
        for (int c = 0; c < CIN; ++c) acc += xv[c] * U[c];
        // d-conv: out[d] = in[d-1]*kd0 + in[d]*kd1 + in[d+1]*kd2, zero pad
        float lm = __shfl_up(acc, 1, 64);
        float rp = __shfl_down(acc, 1, 64);
        if (lane == 0)  lm = 0.f;
        if (lane == 55) rp = 0.f;
        float res = lm * Ukd[r] + acc * Ukd[RK + r] + rp * Ukd[2 * RK + r];
        if (act) T1d[(size_t)r * NP + p] = res;
    }
}

// ---- k3wh4: w-conv + h-conv + 53->64 projection + bias, float4 lanes ----
// Phase 1: wave wv computes t[r] = hblend(wblend(Ta[r,...])) for r=wv, wv+8, ...
//          -> LDS (branchless: offset-select + weight-zero; 9 float4 loads/rank).
// Phase 2: each wave projects 8 out-channels from LDS t[0..52].
// Grid 686 blocks x 512 threads; bijective XCD swizzle for halo L2 locality.
__global__ __launch_bounds__(512, 4) void k3wh4(
    const float4* __restrict__ Ta, const float* __restrict__ Ucout,
    const float* __restrict__ bias, const float* __restrict__ Ukh,
    const float* __restrict__ Ukw, float4* __restrict__ Out)
{
    __shared__ float4 tld[RK][64];               // 53*64*16 = 54,272 B

    const int lane = threadIdx.x & 63;
    const int wv   = threadIdx.x >> 6;           // 0..7

    // bijective XCD swizzle (m204): consecutive q4 chunks per XCD
    const int nwg = gridDim.x;                   // 686
    const int qx = nwg >> 3, rx = nwg & 7;
    const int xcd = blockIdx.x & 7, loc = blockIdx.x >> 3;
    const int swz = ((xcd < rx) ? xcd * (qx + 1) : rx * (qx + 1) + (xcd - rx) * qx) + loc;

    const int q4 = swz * 64 + lane;              // float4 column in [0,NP4)
    const int h  = q4 / H4;
    const int rm = q4 - h * H4;
    const int w  = rm / W4;
    const bool hm = (h > 0), hp = (h < 55);
    const bool wm = (w > 0), wp = (w < 55);
    // boundary -> address select (computed once; all loads below in-bounds)
    const int om = hm ? -H4 : 0;
    const int op = hp ?  H4 : 0;
    const int oa = wm ? -W4 : 0;
    const int oc = wp ?  W4 : 0;

    const float4* Sq = Ta + q4;

    // ---- phase 1: stencil for ranks wv, wv+8, ... ----
#pragma unroll 2
    for (int r = wv; r < RK; r += 8) {
        const float4* S = Sq + (size_t)r * NP4;
        // boundary -> weight zero (cndmask, no branches)
        const float kw0 = wm ? Ukw[r] : 0.f;
        const float kw1 = Ukw[RK + r];
        const float kw2 = wp ? Ukw[2 * RK + r] : 0.f;
        const float kh0 = hm ? Ukh[r] : 0.f;
        const float kh1 = Ukh[RK + r];
        const float kh2 = hp ? Ukh[2 * RK + r] : 0.f;

        // 9 unconditional float4 loads
        float4 v00 = S[om + oa], v01 = S[om], v02 = S[om + oc];
        float4 v10 = S[oa],      v11 = S[0],  v12 = S[oc];
        float4 v20 = S[op + oa], v21 = S[op], v22 = S[op + oc];

        float4 t;
        t.x = (v00.x * kw0 + v01.x * kw1 + v02.x * kw2) * kh0
            + (v10.x * kw0 + v11.x * kw1 + v12.x * kw2) * kh1
            + (v20.x * kw0 + v21.x * kw1 + v22.x * kw2) * kh2;
        t.y = (v00.y * kw0 + v01.y * kw1 + v02.y * kw2) * kh0
            + (v10.y * kw0 + v11.y * kw1 + v12.y * kw2) * kh1
            + (v20.y * kw0 + v21.y * kw1 + v22.y * kw2) * kh2;
        t.z = (v00.z * kw0 + v01.z * kw1 + v02.z * kw2) * kh0
            + (v10.z * kw0 + v11.z * kw1 + v12.z * kw2) * kh1
            + (v20.z * kw0 + v21.z * kw1 + v22.z * kw2) * kh2;
        t.w = (v00.w * kw0 + v01.w * kw1 + v02.w * kw2) * kh0
            + (v10.w * kw0 + v11.w * kw1 + v12.w * kw2) * kh1
            + (v20.w * kw0 + v21.w * kw1 + v22.w * kw2) * kh2;
        tld[r][lane] = t;
    }
    __syncthreads();

    // ---- phase 2: 8-channel projection per wave ----
    const int og = wv << 3;                      // 0,8,...,56 (wave-uniform)
    float4 a[8];
#pragma unroll
    for (int o = 0; o < 8; ++o) {
        float b = bias[og + o];
        a[o].x = b; a[o].y = b; a[o].z = b; a[o].w = b;
    }
#pragma unroll 2
    for (int r = 0; r < RK; ++r) {
        float4 t = tld[r][lane];
        const float* Ur = Ucout + r * COUT + og; // uniform -> s_load
#pragma unroll
        for (int o = 0; o < 8; ++o) {
            float u = Ur[o];
            a[o].x += t.x * u; a[o].y += t.y * u;
            a[o].z += t.z * u; a[o].w += t.w * u;
        }
    }
#pragma unroll
    for (int o = 0; o < 8; ++o)
        Out[(size_t)(og + o) * NP4 + q4] = a[o];
}

// ===================== fallback path (R5, known good) =====================

__global__ __launch_bounds__(256) void k1_chunk(
    const float* __restrict__ x, const float* __restrict__ Ucin,
    float* T, int r0, int nr)
{
    __shared__ float sU[11 * CIN];
    const int tid = threadIdx.x;
    for (int t = tid; t < nr * CIN; t += 256) {
        int lr = t >> 5, c = t & 31;
        sU[t] = Ucin[c * RK + (r0 + lr)];
    }
    __syncthreads();
    const int p = blockIdx.x * 256 + tid;
    float xv[CIN];
#pragma unroll
    for (int c = 0; c < CIN; ++c) xv[c] = x[c * NP + p];
#pragma unroll 1
    for (int lr = 0; lr < nr; ++lr) {
        float acc = 0.f;
#pragma unroll
        for (int c = 0; c < CIN; ++c) acc += xv[c] * sU[lr * CIN + c];
        T[(size_t)(SCR + lr) * NP + p] = acc;
    }
}

__global__ __launch_bounds__(256) void k2_chunk(
    const float* __restrict__ Ukh, const float* __restrict__ Ukw,
    const float* __restrict__ Ukd, float* T, int r0)
{
    __shared__ float sIn[5800];
    __shared__ float sA[5600];
    const int lr = blockIdx.z;
    const int r  = r0 + lr;
    const int h0 = blockIdx.x * 8, w0 = blockIdx.y * 8;
    const int tid = threadIdx.x;
    const float kh0 = Ukh[r], kh1 = Ukh[RK + r], kh2 = Ukh[2 * RK + r];
    const float kw0 = Ukw[r], kw1 = Ukw[RK + r], kw2 = Ukw[2 * RK + r];
    const float kd0 = Ukd[r], kd1 = Ukd[RK + r], kd2 = Ukd[2 * RK + r];
    const float* T1r = T + (size_t)(SCR + lr) * NP;

    for (int idx = tid; idx < 5800; idx += 256) {
        int d = idx % 58; int t2 = idx / 58; int ww = t2 % 10; int hh = t2 / 10;
        int gh = h0 + hh - 1, gw = w0 + ww - 1, gd = d - 1;
        float v = 0.f;
        if ((unsigned)gh < 56u && (unsigned)gw < 56u && (unsigned)gd < 56u)
            v = T1r[gh * HSTR + gw * 56 + gd];
        sIn[idx] = v;
    }
    __syncthreads();
    for (int idx = tid; idx < 5600; idx += 256) {
        int d = idx % 56; int t2 = idx / 56; int ww = t2 % 10; int hh = t2 / 10;
        const float* b = &sIn[(hh * 10 + ww) * 58 + d];
        sA[idx] = b[0] * kd0 + b[1] * kd1 + b[2] * kd2;
    }
    __syncthreads();
    const float k00 = kh0 * kw0, k01 = kh0 * kw1, k02 = kh0 * kw2;
    const float k10 = kh1 * kw0, k11 = kh1 * kw1, k12 = kh1 * kw2;
    const float k20 = kh2 * kw0, k21 = kh2 * kw1, k22 = kh2 * kw2;
    for (int idx = tid; idx < 3584; idx += 256) {
        int d = idx % 56; int t2 = idx / 56; int ww = t2 % 8; int hh = t2 / 8;
        const float* a = &sA[(hh * 10 + ww) * 56 + d];
        float acc = a[0]    * k00 + a[56]   * k01 + a[112]  * k02
                  + a[560]  * k10 + a[616]  * k11 + a[672]  * k12
                  + a[1120] * k20 + a[1176] * k21 + a[1232] * k22;
        T[(size_t)r * NP + (h0 + hh) * HSTR + (w0 + ww) * 56 + d] = acc;
    }
}

__global__ __launch_bounds__(256) void k3_out(
    float* T, const float* __restrict__ Ucout, const float* __restrict__ bias)
{
    __shared__ float sUo[RK * COUT];
    __shared__ float sB[COUT];
    const int tid = threadIdx.x;
    for (int t = tid; t < RK * COUT; t += 256) sUo[t] = Ucout[t];
    if (tid < COUT) sB[tid] = bias[tid];
    __syncthreads();
    const int p = blockIdx.x * 256 + tid;
    float acc[COUT];
#pragma unroll
    for (int o = 0; o < COUT; ++o) acc[o] = sB[o];
#pragma unroll 1
    for (int r = 0; r < RK; ++r) {
        float t = T[(size_t)r * NP + p];
        const float* Ur = &sUo[r * COUT];
#pragma unroll
        for (int o = 0; o < COUT; ++o) acc[o] += t * Ur[o];
    }
#pragma unroll
    for (int o = 0; o < COUT; ++o) T[(size_t)o * NP + p] = acc[o];
}

// ===================== launch =====================

extern "C" void kernel_launch(void* const* d_in, const int* in_sizes, int n_in,
                              void* d_out, int out_size, void* d_ws, size_t ws_size,
                              hipStream_t stream)
{
    const float* x     = (const float*)d_in[0];
    const float* Ukh   = (const float*)d_in[1];
    const float* Ukw   = (const float*)d_in[2];
    const float* Ukd   = (const float*)d_in[3];
    const float* Ucin  = (const float*)d_in[4];
    const float* Ucout = (const float*)d_in[5];
    const float* bias  = (const float*)d_in[6];

    const size_t t1_bytes = (size_t)RK * NP * sizeof(float);   // 37.2 MB

    if (ws_size >= t1_bytes + 8192) {
        float* T1 = (float*)d_ws;
        float* Ut = (float*)((char*)d_ws + t1_bytes);          // 6.8 KB
        k0_t<<<7, 256, 0, stream>>>(Ucin, Ut);
        k1d<<<HSTR / 4, 256, 0, stream>>>(x, Ut, Ukd, T1);     // 784 blocks
        k3wh4<<<NP4 / 64, 512, 0, stream>>>((const float4*)T1, Ucout, bias, Ukh,
                                            Ukw, (float4*)d_out);   // 686 blocks
    } else {
        float* T = (float*)d_out;
        for (int r0 = 0; r0 < RK; r0 += 11) {
            int nr = (RK - r0 < 11) ? (RK - r0) : 11;
            k1_chunk<<<NP / 256, 256, 0, stream>>>(x, Ucin, T, r0, nr);
            k2_chunk<<<dim3(7, 7, nr), 256, 0, stream>>>(Ukh, Ukw, Ukd, T, r0);
        }
        k3_out<<<NP / 256, 256, 0, stream>>>(T, Ucout, bias);
    }
}